// Round 17
// baseline (218.642 us; speedup 1.0000x reference)
//
#include <hip/hip_runtime.h>
#include <math.h>

#define D_MODEL 1024
#define SEQ     1024
#define BATCH   4
#define NTOK    (BATCH * SEQ)   // 4096

typedef __bf16 bf16;
using bfrag  = __attribute__((ext_vector_type(8))) __bf16;
using ffrag  = __attribute__((ext_vector_type(4))) float;
using f32x16 = __attribute__((ext_vector_type(16))) float;

__device__ __forceinline__ ffrag mfma16(bfrag a, bfrag b, ffrag c) {
  return __builtin_amdgcn_mfma_f32_16x16x32_bf16(a, b, c, 0, 0, 0);
}
__device__ __forceinline__ f32x16 mfma32(bfrag a, bfrag b, f32x16 c) {
  return __builtin_amdgcn_mfma_f32_32x32x16_bf16(a, b, c, 0, 0, 0);
}
__device__ __forceinline__ unsigned cvt_pk(float lo, float hi) {
  unsigned r;
  asm("v_cvt_pk_bf16_f32 %0, %1, %2" : "=v"(r) : "v"(lo), "v"(hi));
  return r;
}

__device__ __forceinline__ void gload_lds16(const void* g, void* l) {
  __builtin_amdgcn_global_load_lds(
      (const __attribute__((address_space(1))) void*)g,
      (__attribute__((address_space(3))) void*)l, 16, 0, 0);
}

__device__ __forceinline__ void barrier_raw() {
  asm volatile("" ::: "memory");
  __builtin_amdgcn_s_barrier();
  asm volatile("" ::: "memory");
}

// XCD-aware bijective block remap (T1); only where per-XCD slices cache-fit.
__device__ __forceinline__ int xcd_remap(int flat, int nwg) {
  return (flat & 7) * (nwg >> 3) + (flat >> 3);
}

// ---------------------------------------------------------------- all weights fp32 -> bf16 (one launch)
__global__ void convert_all(const float* __restrict__ s0, bf16* __restrict__ d0, int n0,
                            const float* __restrict__ s1, bf16* __restrict__ d1, int n1,
                            const float* __restrict__ s2, bf16* __restrict__ d2, int n2,
                            const float* __restrict__ s3, bf16* __restrict__ d3, int n3,
                            float scale, int limit0) {
  const float* src; bf16* dst; int n; int limit = 0;
  switch (blockIdx.y) {
    case 0: src = s0; dst = d0; n = n0; limit = limit0; break;
    case 1: src = s1; dst = d1; n = n1; break;
    case 2: src = s2; dst = d2; n = n2; break;
    default: src = s3; dst = d3; n = n3; break;
  }
  int i = blockIdx.x * blockDim.x + threadIdx.x;
  const int stride = gridDim.x * blockDim.x;
  for (; i < n; i += stride) {
    float4 v = ((const float4*)src)[i];
    float sc = (i < limit) ? scale : 1.0f;
    bf16* d = dst + (size_t)i * 4;
    d[0] = (bf16)(v.x * sc); d[1] = (bf16)(v.y * sc);
    d[2] = (bf16)(v.z * sc); d[3] = (bf16)(v.w * sc);
  }
}

__global__ void scale_bias(const float* __restrict__ src, float* __restrict__ dst,
                           int n, int limit, float scale) {
  int i = blockIdx.x * blockDim.x + threadIdx.x;
  if (i < n) dst[i] = src[i] * (i < limit ? scale : 1.0f);
}

// ---------------------------------------------------------------- LayerNorm (fp32 in, bf16 out)
__global__ __launch_bounds__(256) void ln_row(const float* __restrict__ x,
                                              const float* __restrict__ gamma,
                                              const float* __restrict__ beta,
                                              bf16* __restrict__ out) {
  const int row = blockIdx.x, tid = threadIdx.x;
  const float4 v = ((const float4*)(x + (size_t)row * D_MODEL))[tid];
  float s  = v.x + v.y + v.z + v.w;
  float ss = v.x * v.x + v.y * v.y + v.z * v.z + v.w * v.w;
#pragma unroll
  for (int off = 32; off >= 1; off >>= 1) {
    s  += __shfl_xor(s, off);
    ss += __shfl_xor(ss, off);
  }
  __shared__ float rs[4], rss[4];
  const int w = tid >> 6;
  if ((tid & 63) == 0) { rs[w] = s; rss[w] = ss; }
  __syncthreads();
  s  = rs[0] + rs[1] + rs[2] + rs[3];
  ss = rss[0] + rss[1] + rss[2] + rss[3];
  const float mu   = s * (1.0f / D_MODEL);
  const float var  = ss * (1.0f / D_MODEL) - mu * mu;
  const float rstd = rsqrtf(var + 1e-5f);
  const float4 gv = ((const float4*)gamma)[tid];
  const float4 bv = ((const float4*)beta)[tid];
  bf16* o = out + (size_t)row * D_MODEL + tid * 4;
  o[0] = (bf16)((v.x - mu) * rstd * gv.x + bv.x);
  o[1] = (bf16)((v.y - mu) * rstd * gv.y + bv.y);
  o[2] = (bf16)((v.z - mu) * rstd * gv.z + bv.z);
  o[3] = (bf16)((v.w - mu) * rstd * gv.w + bv.w);
}

// ---------------------------------------------------------------- GEMM 256x256 8-phase (QKV, FC) — T3+T4 port
// 512 thr = 8 waves (2M x 4N), wave tile 128x64, BK=64, LDS 128KB dynamic
// (2 dbuf x 2 halves x 128x64 x {A,B}). Per K-tile: 4 phases, each = one
// 64x32 C-quadrant x K=64 (16 MFMA) interleaved with 12 ds_read_b128 and one
// half-tile prefetch (2 gload_lds). Counted vmcnt(2) once per K-tile at
// phase 0 (never 0 mid-loop): waits current tile's 8 loads, just-issued
// prefetch stays in flight; the phase-0 barrier then certifies all waves'
// DMA landed. Per-phase lgkmcnt(0)+barrier seals buffer reads before reuse.
// EPI 0: +bias->bf16 | EPI 2: +bias+QuickGELU->bf16
template <int EPI>
__global__ __launch_bounds__(512, 2) void gemm256(
    const bf16* __restrict__ A, const bf16* __restrict__ B,
    const float* __restrict__ bias, bf16* __restrict__ outB,
    int M, int N, int K) {
  extern __shared__ bf16 sm[];           // 65536 els: A 32768 | B 32768
  const int tid = threadIdx.x;
  const int lane = tid & 63, wid = tid >> 6;
  const int wm = wid >> 2, wn = wid & 3;
  const int ql = lane & 15, lg = lane >> 4;
  const int gx = M >> 8;
  const int flat = xcd_remap(blockIdx.x, gridDim.x);
  const int m0 = (flat % gx) << 8, n0 = (flat / gx) << 8;

  auto aslot = [&](int buf, int half) { return sm + ((buf * 2 + half) << 13); };
  auto bslot = [&](int buf, int half) { return sm + 32768 + ((buf * 2 + half) << 13); };

  ffrag acc[8][4];
#pragma unroll
  for (int a = 0; a < 8; a++)
#pragma unroll
    for (int b = 0; b < 4; b++) acc[a][b] = ffrag{0.f, 0.f, 0.f, 0.f};

  // staging: thread covers rows r0 / r0+64 of a 128-row half, chunk (tid&7)^(r0&7)
  const int r0 = tid >> 3;
  const int jsw = ((tid & 7) ^ (r0 & 7)) * 8;
  const bf16* ag = A + (size_t)(m0 + r0) * K + jsw;
  const bf16* bg = B + (size_t)(n0 + r0) * K + jsw;

  auto STAGE_A = [&](int bs, int half, int kk) {
    bf16* d = aslot(bs, half);
    gload_lds16(ag + (size_t)(half * 128) * K + kk, d + tid * 8);
    gload_lds16(ag + (size_t)(half * 128 + 64) * K + kk, d + 4096 + tid * 8);
  };
  auto STAGE_B = [&](int bs, int half, int kk) {
    bf16* d = bslot(bs, half);
    gload_lds16(bg + (size_t)(half * 128) * K + kk, d + tid * 8);
    gload_lds16(bg + (size_t)(half * 128 + 64) * K + kk, d + 4096 + tid * 8);
  };

  bfrag af[4][2], bfr[2][2];
  auto LOADQ = [&](int q, int buf) {
    const int qm = q >> 1, qn = q & 1;
    const bf16* as = aslot(buf, wm);
    const bf16* bs = bslot(buf, wn >> 1);
#pragma unroll
    for (int i = 0; i < 4; i++) {
      const int rih = qm * 64 + i * 16 + ql;
#pragma unroll
      for (int kc = 0; kc < 2; kc++)
        af[i][kc] = *(const bfrag*)&as[rih * 64 + (((kc * 4 + lg) ^ (rih & 7)) * 8)];
    }
#pragma unroll
    for (int j = 0; j < 2; j++) {
      const int cih = (wn & 1) * 64 + qn * 32 + j * 16 + ql;
#pragma unroll
      for (int kc = 0; kc < 2; kc++)
        bfr[j][kc] = *(const bfrag*)&bs[cih * 64 + (((kc * 4 + lg) ^ (cih & 7)) * 8)];
    }
  };
  auto MFMAQ = [&](int q) {
    const int qm = q >> 1, qn = q & 1;
    __builtin_amdgcn_s_setprio(1);
#pragma unroll
    for (int kc = 0; kc < 2; kc++)
#pragma unroll
      for (int i = 0; i < 4; i++)
#pragma unroll
        for (int j = 0; j < 2; j++)
          acc[qm * 4 + i][qn * 2 + j] =
              mfma16(af[i][kc], bfr[j][kc], acc[qm * 4 + i][qn * 2 + j]);
    __builtin_amdgcn_s_setprio(0);
  };

  // prologue: stage K-tile 0 fully (8 loads); loop's phase-0 wait covers it
  STAGE_A(0, 0, 0); STAGE_A(0, 1, 0); STAGE_B(0, 0, 0); STAGE_B(0, 1, 0);

  const int NT = K >> 6;
  for (int t = 0; t < NT; ++t) {
    const int buf = t & 1, nxt = buf ^ 1;
    const int kn = (t + 1) << 6;
    const bool pf = (t + 1 < NT);
    // ---- phase 0 (certify tile t; prefetch A-h0 of t+1)
    if (pf) {
      STAGE_A(nxt, 0, kn);
      asm volatile("s_waitcnt vmcnt(2)" ::: "memory");
    } else {
      asm volatile("s_waitcnt vmcnt(0)" ::: "memory");
    }
    barrier_raw();
    __builtin_amdgcn_sched_barrier(0);
    LOADQ(0, buf);
    asm volatile("s_waitcnt lgkmcnt(0)" ::: "memory");
    __builtin_amdgcn_sched_barrier(0);
    MFMAQ(0);
    barrier_raw();
    // ---- phase 1 (prefetch A-h1)
    LOADQ(1, buf);
    if (pf) STAGE_A(nxt, 1, kn);
    barrier_raw();
    asm volatile("s_waitcnt lgkmcnt(0)" ::: "memory");
    __builtin_amdgcn_sched_barrier(0);
    MFMAQ(1);
    barrier_raw();
    // ---- phase 2 (prefetch B-h0)
    LOADQ(2, buf);
    if (pf) STAGE_B(nxt, 0, kn);
    barrier_raw();
    asm volatile("s_waitcnt lgkmcnt(0)" ::: "memory");
    __builtin_amdgcn_sched_barrier(0);
    MFMAQ(2);
    barrier_raw();
    // ---- phase 3 (prefetch B-h1)
    LOADQ(3, buf);
    if (pf) STAGE_B(nxt, 1, kn);
    barrier_raw();
    asm volatile("s_waitcnt lgkmcnt(0)" ::: "memory");
    __builtin_amdgcn_sched_barrier(0);
    MFMAQ(3);
    barrier_raw();
  }
  asm volatile("" ::: "memory");

#pragma unroll
  for (int a = 0; a < 8; a++) {
    const int row = m0 + wm * 128 + (a >> 2) * 64 + (a & 3) * 16 + lg * 4;
#pragma unroll
    for (int b = 0; b < 4; b++) {
      const int col = n0 + wn * 64 + (b >> 1) * 32 + (b & 1) * 16 + ql;
      const float bv = bias[col];
#pragma unroll
      for (int r = 0; r < 4; r++) {
        float v = acc[a][b][r] + bv;
        const size_t idx = (size_t)(row + r) * N + col;
        if (EPI == 0) outB[idx] = (bf16)v;
        else          outB[idx] = (bf16)(v / (1.0f + __expf(-1.702f * v)));
      }
    }
  }
}

// ---------------------------------------------------------------- GEMM 64x64 (out, proj) — round-14 proven
template <int EPI>
__global__ __launch_bounds__(256, 4) void gemm_bt64(
    const bf16* __restrict__ A, const bf16* __restrict__ B,
    const float* __restrict__ bias, const float* __restrict__ resid,
    float* __restrict__ outF, bf16* __restrict__ outB,
    int M, int N, int K) {
  __shared__ bf16 As[2][64 * 64];
  __shared__ bf16 Bs[2][64 * 64];
  const int tid = threadIdx.x;
  const int lane = tid & 63, w = tid >> 6;
  const int wm = w >> 1, wn = w & 1;
  const int ql = lane & 15, lg = lane >> 4;
  const int bid = blockIdx.x;
  const int k8 = bid & 7, j8 = bid >> 3;
  const int m0 = (k8 * 8 + (j8 & 7)) * 64;
  const int n0 = (j8 >> 3) * 64;

  ffrag acc[2][2];
#pragma unroll
  for (int i = 0; i < 2; i++)
#pragma unroll
    for (int j = 0; j < 2; j++) acc[i][j] = ffrag{0.f, 0.f, 0.f, 0.f};

  const int r0 = tid >> 3;
  const int jsw = ((tid & 7) ^ (r0 & 7)) * 8;
  const bf16* a0 = A + (size_t)(m0 + r0) * K + jsw;
  const bf16* a1 = A + (size_t)(m0 + 32 + r0) * K + jsw;
  const bf16* b0 = B + (size_t)(n0 + r0) * K + jsw;
  const bf16* b1 = B + (size_t)(n0 + 32 + r0) * K + jsw;
  const int lo = tid * 8;

  auto STAGE = [&](int bs, int kk) {
    gload_lds16(a0 + kk, &As[bs][lo]);
    gload_lds16(a1 + kk, &As[bs][2048 + lo]);
    gload_lds16(b0 + kk, &Bs[bs][lo]);
    gload_lds16(b1 + kk, &Bs[bs][2048 + lo]);
  };

  STAGE(0, 0);
  __syncthreads();

  int cur = 0;
  for (int k0 = 0; k0 < K; k0 += 64) {
    if (k0 + 64 < K) STAGE(cur ^ 1, k0 + 64);
    bfrag af[2][2], bfr[2][2];
#pragma unroll
    for (int i = 0; i < 2; i++) {
      const int row = wm * 32 + i * 16 + ql;
      const int r7 = row & 7;
#pragma unroll
      for (int kc = 0; kc < 2; kc++)
        af[i][kc] = *(const bfrag*)&As[cur][row * 64 + (((lg + 4 * kc) ^ r7) * 8)];
    }
#pragma unroll
    for (int j = 0; j < 2; j++) {
      const int row = wn * 32 + j * 16 + ql;
      const int r7 = row & 7;
#pragma unroll
      for (int kc = 0; kc < 2; kc++)
        bfr[j][kc] = *(const bfrag*)&Bs[cur][row * 64 + (((lg + 4 * kc) ^ r7) * 8)];
    }
#pragma unroll
    for (int kc = 0; kc < 2; kc++)
#pragma unroll
      for (int i = 0; i < 2; i++)
#pragma unroll
        for (int j = 0; j < 2; j++)
          acc[i][j] = mfma16(af[i][kc], bfr[j][kc], acc[i][j]);
    __syncthreads();
    cur ^= 1;
  }

#pragma unroll
  for (int i = 0; i < 2; i++) {
    const int row = m0 + wm * 32 + i * 16 + lg * 4;
#pragma unroll
    for (int j = 0; j < 2; j++) {
      const int col = n0 + wn * 32 + j * 16 + ql;
      const float bv = bias[col];
#pragma unroll
      for (int r = 0; r < 4; r++) {
        float v = acc[i][j][r] + bv;
        const size_t idx = (size_t)(row + r) * N + col;
        if (EPI == 0) {
          outB[idx] = (bf16)v;
        } else if (EPI == 1) {
          outF[idx] = v + resid[idx];
        } else {
          outB[idx] = (bf16)(v / (1.0f + __expf(-1.702f * v)));
        }
      }
    }
  }
}

// ---------------------------------------------------------------- V transpose: qkv V-part -> VT[b][h][d][s]
__global__ __launch_bounds__(256) void transpose_v(const bf16* __restrict__ qkv,
                                                   bf16* __restrict__ vt) {
  __shared__ bf16 T[64 * 66];
  const int tid = threadIdx.x;
  const int bh = blockIdx.y, b = bh >> 4, h = bh & 15;
  const int s0 = blockIdx.x * 64;
  const bf16* src = qkv + (size_t)b * SEQ * 3072 + 2048 + h * 64;

  const int sl = tid >> 3, c = tid & 7;
#pragma unroll
  for (int p = 0; p < 2; p++) {
    const int s = sl + p * 32;
    const bfrag v = *(const bfrag*)(src + (size_t)(s0 + s) * 3072 + c * 8);
#pragma unroll
    for (int e = 0; e < 8; e++) T[s * 66 + c * 8 + e] = v[e];
  }
  __syncthreads();
  bf16* dst = vt + (size_t)bh * 64 * 1024;
#pragma unroll
  for (int p = 0; p < 2; p++) {
    const int d = sl + p * 32;
    bfrag o;
#pragma unroll
    for (int e = 0; e < 8; e++) o[e] = T[(c * 8 + e) * 66 + d];
    *(bfrag*)(dst + (size_t)d * 1024 + s0 + c * 8) = o;
  }
}

// ---------------------------------------------------------------- flash attention v9 (round-16 state)
__global__ __launch_bounds__(256, 2) void flash_attn(const bf16* __restrict__ qkv,
                                                     const bf16* __restrict__ vt,
                                                     bf16* __restrict__ o) {
  __shared__ bf16 Kl[2][128 * 64];
  __shared__ bf16 Vl[2][64 * 128];
  __shared__ float RB[4][32];
  const int tid = threadIdx.x, lane = tid & 63, wid = tid >> 6;
  const int l31 = lane & 31, hi = lane >> 5;
  const int flat = xcd_remap(blockIdx.y * 8 + blockIdx.x, 512);
  const int qblk = flat & 7, bh = flat >> 3, b = bh >> 4, h = bh & 15;
  const int qb0 = qblk * 128 + wid * 32;
  const size_t headq = (size_t)b * SEQ * 3072 + (size_t)h * 64;

  const bf16* qp = qkv + headq + (size_t)(qb0 + l31) * 3072 + hi * 8;
  bfrag qb[4];
#pragma unroll
  for (int t = 0; t < 4; t++) qb[t] = *(const bfrag*)(qp + t * 16);

  float mrun = -1e30f, lrun = 0.0f;
  f32x16 oacc[2];
#pragma unroll
  for (int r = 0; r < 16; r++) { oacc[0][r] = 0.f; oacc[1][r] = 0.f; }

  const int ksrc = ((tid & 7) ^ ((tid >> 3) & 7) ^ wid) * 8;
  const bf16* kp = qkv + headq + 1024 + (size_t)(tid >> 3) * 3072 + ksrc;
  const bf16* vhead = vt + (size_t)bh * 64 * 1024;
  const int xlane = (l31 & 7) ^ (l31 >> 3);

  auto STAGE = [&](int bs, int kt) {
#pragma unroll
    for (int pp = 0; pp < 4; pp++)
      gload_lds16(kp + (size_t)(kt + pp * 32) * 3072, &Kl[bs][pp * 2048 + tid * 8]);
#pragma unroll
    for (int pp = 0; pp < 4; pp++) {
      const int vr = pp * 16 + (tid >> 4);
      const int gc = (tid & 15) ^ ((tid >> 4) & 7) ^ ((pp * 2 + (tid >> 7)) & 3);
      gload_lds16(vhead + (size_t)vr * 1024 + kt + gc * 8, &Vl[bs][(pp * 256 + tid) * 8]);
    }
  };

  STAGE(0, 0);
  __syncthreads();

  int cur = 0;
  for (int kt = 0; kt < SEQ; kt += 128) {
    if (kt + 128 < SEQ) STAGE(cur ^ 1, kt + 128);

    f32x16 sacc[4];
#pragma unroll
    for (int s = 0; s < 4; s++)
#pragma unroll
      for (int r = 0; r < 16; r++) sacc[s][r] = 0.f;
    __builtin_amdgcn_s_setprio(1);
#pragma unroll
    for (int s = 0; s < 4; s++) {
      const int krow = s * 32 + l31;
#pragma unroll
      for (int t = 0; t < 4; t++) {
        const int ch = (t * 2) ^ hi ^ xlane;
        const bfrag kf = *(const bfrag*)&Kl[cur][krow * 64 + ch * 8];
        sacc[s] = mfma32(kf, qb[t], sacc[s]);
      }
    }
    __builtin_amdgcn_s_setprio(0);

    float lm = sacc[0][0];
#pragma unroll
    for (int s = 0; s < 4; s++)
#pragma unroll
      for (int r = 0; r < 16; r++) lm = fmaxf(lm, sacc[s][r]);

    if (!__all(lm - mrun <= 8.0f)) {
      const float mx = fmaxf(lm, __shfl_xor(lm, 32));
      const float mnew = fmaxf(mrun, mx);
      const float corr = exp2f(mrun - mnew);
      mrun = mnew;
      lrun *= corr;
      if (!hi) RB[wid][l31] = corr;
#pragma unroll
      for (int r = 0; r < 16; r++) {
        const float c = RB[wid][(r & 3) + 8 * (r >> 2) + 4 * hi];
        oacc[0][r] *= c;
        oacc[1][r] *= c;
      }
    }

#pragma unroll
    for (int s = 0; s < 4; s++) {
      float p[16];
#pragma unroll
      for (int r = 0; r < 16; r++) p[r] = exp2f(sacc[s][r] - mrun);
#pragma unroll
      for (int r = 0; r < 16; r++) lrun += p[r];
      const unsigned A = cvt_pk(p[0], p[1]),  B = cvt_pk(p[2], p[3]);
      const unsigned C = cvt_pk(p[4], p[5]),  D = cvt_pk(p[6], p[7]);
      const unsigned E = cvt_pk(p[8], p[9]),  F = cvt_pk(p[10], p[11]);
      const unsigned G = cvt_pk(p[12], p[13]), H = cvt_pk(p[14], p[15]);
      const unsigned x1 = __shfl_xor(hi ? A : C, 32);
      const unsigned x2 = __shfl_xor(hi ? B : D, 32);
      const unsigned x3 = __shfl_xor(hi ? E : G, 32);
      const unsigned x4 = __shfl_xor(hi ? F : H, 32);
      unsigned w0[4] = { hi ? x1 : A, hi ? x2 : B, hi ? C : x1, hi ? D : x2 };
      unsigned w1[4] = { hi ? x3 : E, hi ? x4 : F, hi ? G : x3, hi ? H : x4 };
      const bfrag pa0 = *(const bfrag*)w0;
      const bfrag pa1 = *(const bfrag*)w1;
      __builtin_amdgcn_s_setprio(1);
#pragma unroll
      for (int db = 0; db < 2; db++) {
        const int vrow = db * 32 + l31;
        const bfrag vf0 = *(const bfrag*)&Vl[cur][vrow * 128 + ((((2 * s) * 2) ^ hi ^ xlane) & 15) * 8];
        oacc[db] = mfma32(pa0, vf0, oacc[db]);
        const bfrag vf1 = *(const bfrag*)&Vl[cur][vrow * 128 + ((((2 * s + 1) * 2) ^ hi ^ xlane) & 15) * 8];
        oacc[db] = mfma32(pa1, vf1, oacc[db]);
      }
      __builtin_amdgcn_s_setprio(0);
    }
    __syncthreads();
    cur ^= 1;
  }

  const float lsum = lrun + __shfl_xor(lrun, 32);
  if (!hi) RB[wid][l31] = 1.0f / lsum;
#pragma unroll
  for (int r = 0; r < 16; r++) {
    const int qml = (r & 3) + 8 * (r >> 2) + 4 * hi;
    const float rv = RB[wid][qml];
    const size_t orow = (size_t)b * SEQ + qb0 + qml;
    o[orow * 1024 + h * 64 + l31]      = (bf16)(oacc[0][r] * rv);
    o[orow * 1024 + h * 64 + 32 + l31] = (bf16)(oacc[1][r] * rv);
  }
}

// ---------------------------------------------------------------- launch
extern "C" void kernel_launch(void* const* d_in, const int* in_sizes, int n_in,
                              void* d_out, int out_size, void* d_ws, size_t ws_size,
                              hipStream_t stream) {
  (void)in_sizes; (void)n_in; (void)out_size; (void)ws_size;
  const float* x      = (const float*)d_in[0];
  const float* in_w   = (const float*)d_in[1];
  const float* in_b   = (const float*)d_in[2];
  const float* out_w  = (const float*)d_in[3];
  const float* out_b  = (const float*)d_in[4];
  const float* ln1_g  = (const float*)d_in[5];
  const float* ln1_b  = (const float*)d_in[6];
  const float* fc_w   = (const float*)d_in[7];
  const float* fc_b   = (const float*)d_in[8];
  const float* proj_w = (const float*)d_in[9];
  const float* proj_b = (const float*)d_in[10];
  const float* ln2_g  = (const float*)d_in[11];
  const float* ln2_b  = (const float*)d_in[12];
  float* out = (float*)d_out;

  char* p = (char*)d_ws;
  auto alloc = [&](size_t bytes) { char* r = p; p += (bytes + 255) & ~255ull; return r; };
  bf16* w_qkv  = (bf16*)alloc((size_t)3072 * 1024 * 2);
  bf16* w_out  = (bf16*)alloc((size_t)1024 * 1024 * 2);
  bf16* w_fc   = (bf16*)alloc((size_t)4096 * 1024 * 2);
  bf16* w_proj = (bf16*)alloc((size_t)1024 * 4096 * 2);
  float* b_qkv = (float*)alloc((size_t)3072 * 4);
  bf16* hbuf   = (bf16*)alloc((size_t)NTOK * 1024 * 2);   // LN1 out; reused as LN2 out
  float* x2    = (float*)alloc((size_t)NTOK * 1024 * 4);
  bf16* qkv    = (bf16*)alloc((size_t)NTOK * 3072 * 2);
  bf16* aout   = (bf16*)alloc((size_t)NTOK * 1024 * 2);
  bf16* ubuf   = qkv;              // aliases qkv+aout (both dead by GEMM3)
  bf16* vtb    = (bf16*)x2;        // VT [64 bh][64 d][1024 s] = 8MB; x2 written only after flash

  // fold head-scaling AND log2(e) (log2-domain softmax) into q weights+bias
  const float scaling = 0.125f * 1.44269504089f;
  convert_all<<<dim3(1024, 4), 256, 0, stream>>>(
      in_w, w_qkv, 3072 * 1024 / 4,
      out_w, w_out, 1024 * 1024 / 4,
      fc_w, w_fc, 4096 * 1024 / 4,
      proj_w, w_proj, 4096 * 1024 / 4,
      scaling, 1024 * 1024 / 4);
  scale_bias<<<12, 256, 0, stream>>>(in_b, b_qkv, 3072, 1024, scaling);

  ln_row<<<NTOK, 256, 0, stream>>>(x, ln1_g, ln1_b, hbuf);
  gemm256<0><<<16 * 12, 512, 131072, stream>>>(hbuf, w_qkv, b_qkv, qkv,
                                               NTOK, 3072, 1024);
  transpose_v<<<dim3(16, 64), 256, 0, stream>>>(qkv, vtb);
  flash_attn<<<dim3(8, 64), 256, 0, stream>>>(qkv, vtb, aout);
  gemm_bt64<1><<<1024, 256, 0, stream>>>(aout, w_out, out_b, x,
                                         x2, nullptr, NTOK, 1024, 1024);
  ln_row<<<NTOK, 256, 0, stream>>>(x2, ln2_g, ln2_b, hbuf);
  gemm256<2><<<16 * 16, 512, 131072, stream>>>(hbuf, w_fc, fc_b, ubuf,
                                               NTOK, 4096, 1024);
  gemm_bt64<1><<<1024, 256, 0, stream>>>(ubuf, w_proj, proj_b, x2,
                                         out, nullptr, NTOK, 1024, 4096);
}

// Round 18
// 216.262 us; speedup vs baseline: 1.0110x; 1.0110x over previous
//
#include <hip/hip_runtime.h>
#include <math.h>

#define D_MODEL 1024
#define SEQ     1024
#define BATCH   4
#define NTOK    (BATCH * SEQ)   // 4096

typedef __bf16 bf16;
using bfrag  = __attribute__((ext_vector_type(8))) __bf16;
using ffrag  = __attribute__((ext_vector_type(4))) float;
using f32x16 = __attribute__((ext_vector_type(16))) float;

__device__ __forceinline__ ffrag mfma16(bfrag a, bfrag b, ffrag c) {
  return __builtin_amdgcn_mfma_f32_16x16x32_bf16(a, b, c, 0, 0, 0);
}
__device__ __forceinline__ f32x16 mfma32(bfrag a, bfrag b, f32x16 c) {
  return __builtin_amdgcn_mfma_f32_32x32x16_bf16(a, b, c, 0, 0, 0);
}
__device__ __forceinline__ unsigned cvt_pk(float lo, float hi) {
  unsigned r;
  asm("v_cvt_pk_bf16_f32 %0, %1, %2" : "=v"(r) : "v"(lo), "v"(hi));
  return r;
}

__device__ __forceinline__ void gload_lds16(const void* g, void* l) {
  __builtin_amdgcn_global_load_lds(
      (const __attribute__((address_space(1))) void*)g,
      (__attribute__((address_space(3))) void*)l, 16, 0, 0);
}

// XCD-aware bijective block remap (T1); only where per-XCD slices cache-fit.
__device__ __forceinline__ int xcd_remap(int flat, int nwg) {
  return (flat & 7) * (nwg >> 3) + (flat >> 3);
}

// ---------------------------------------------------------------- all weights fp32 -> bf16 (one launch)
__global__ void convert_all(const float* __restrict__ s0, bf16* __restrict__ d0, int n0,
                            const float* __restrict__ s1, bf16* __restrict__ d1, int n1,
                            const float* __restrict__ s2, bf16* __restrict__ d2, int n2,
                            const float* __restrict__ s3, bf16* __restrict__ d3, int n3,
                            float scale, int limit0) {
  const float* src; bf16* dst; int n; int limit = 0;
  switch (blockIdx.y) {
    case 0: src = s0; dst = d0; n = n0; limit = limit0; break;
    case 1: src = s1; dst = d1; n = n1; break;
    case 2: src = s2; dst = d2; n = n2; break;
    default: src = s3; dst = d3; n = n3; break;
  }
  int i = blockIdx.x * blockDim.x + threadIdx.x;
  const int stride = gridDim.x * blockDim.x;
  for (; i < n; i += stride) {
    float4 v = ((const float4*)src)[i];
    float sc = (i < limit) ? scale : 1.0f;
    bf16* d = dst + (size_t)i * 4;
    d[0] = (bf16)(v.x * sc); d[1] = (bf16)(v.y * sc);
    d[2] = (bf16)(v.z * sc); d[3] = (bf16)(v.w * sc);
  }
}

__global__ void scale_bias(const float* __restrict__ src, float* __restrict__ dst,
                           int n, int limit, float scale) {
  int i = blockIdx.x * blockDim.x + threadIdx.x;
  if (i < n) dst[i] = src[i] * (i < limit ? scale : 1.0f);
}

// ---------------------------------------------------------------- LayerNorm (fp32 in, bf16 out)
__global__ __launch_bounds__(256) void ln_row(const float* __restrict__ x,
                                              const float* __restrict__ gamma,
                                              const float* __restrict__ beta,
                                              bf16* __restrict__ out) {
  const int row = blockIdx.x, tid = threadIdx.x;
  const float4 v = ((const float4*)(x + (size_t)row * D_MODEL))[tid];
  float s  = v.x + v.y + v.z + v.w;
  float ss = v.x * v.x + v.y * v.y + v.z * v.z + v.w * v.w;
#pragma unroll
  for (int off = 32; off >= 1; off >>= 1) {
    s  += __shfl_xor(s, off);
    ss += __shfl_xor(ss, off);
  }
  __shared__ float rs[4], rss[4];
  const int w = tid >> 6;
  if ((tid & 63) == 0) { rs[w] = s; rss[w] = ss; }
  __syncthreads();
  s  = rs[0] + rs[1] + rs[2] + rs[3];
  ss = rss[0] + rss[1] + rss[2] + rss[3];
  const float mu   = s * (1.0f / D_MODEL);
  const float var  = ss * (1.0f / D_MODEL) - mu * mu;
  const float rstd = rsqrtf(var + 1e-5f);
  const float4 gv = ((const float4*)gamma)[tid];
  const float4 bv = ((const float4*)beta)[tid];
  bf16* o = out + (size_t)row * D_MODEL + tid * 4;
  o[0] = (bf16)((v.x - mu) * rstd * gv.x + bv.x);
  o[1] = (bf16)((v.y - mu) * rstd * gv.y + bv.y);
  o[2] = (bf16)((v.z - mu) * rstd * gv.z + bv.z);
  o[3] = (bf16)((v.w - mu) * rstd * gv.w + bv.w);
}

// ---------------------------------------------------------------- GEMM 128x128 (QKV, FC) — round-10/14 proven
template <int EPI>
__global__ __launch_bounds__(256, 4) void gemm_bt(
    const bf16* __restrict__ A, const bf16* __restrict__ B,
    const float* __restrict__ bias, const float* __restrict__ resid,
    float* __restrict__ outF, bf16* __restrict__ outB,
    int M, int N, int K) {
  __shared__ bf16 As[2][128 * 32];
  __shared__ bf16 Bs[2][128 * 32];
  const int tid = threadIdx.x;
  const int lane = tid & 63, w = tid >> 6;
  const int wm = w >> 1, wn = w & 1;
  const int ql = lane & 15, lg = lane >> 4;
  const int nwg = gridDim.x * gridDim.y;
  const int flat = xcd_remap(blockIdx.y * gridDim.x + blockIdx.x, nwg);
  const int m0 = (flat % gridDim.x) * 128, n0 = (flat / gridDim.x) * 128;

  ffrag acc[4][4];
#pragma unroll
  for (int i = 0; i < 4; i++)
#pragma unroll
    for (int j = 0; j < 4; j++) acc[i][j] = ffrag{0.f, 0.f, 0.f, 0.f};

  const int r0 = tid >> 2;
  const int jsw = (tid & 3) ^ ((r0 >> 1) & 3);
  const bf16* a0 = A + (size_t)(m0 + r0) * K + jsw * 8;
  const bf16* a1 = A + (size_t)(m0 + 64 + r0) * K + jsw * 8;
  const bf16* b0 = B + (size_t)(n0 + r0) * K + jsw * 8;
  const bf16* b1 = B + (size_t)(n0 + 64 + r0) * K + jsw * 8;
  const int lo = w * 512;

  auto STAGE = [&](int bs, int kk) {
    gload_lds16(a0 + kk, &As[bs][lo]);
    gload_lds16(a1 + kk, &As[bs][2048 + lo]);
    gload_lds16(b0 + kk, &Bs[bs][lo]);
    gload_lds16(b1 + kk, &Bs[bs][2048 + lo]);
  };

  STAGE(0, 0);
  __syncthreads();

  int cur = 0;
  for (int k0 = 0; k0 < K; k0 += 32) {
    if (k0 + 32 < K) STAGE(cur ^ 1, k0 + 32);
    bfrag af[4], bfr[4];
#pragma unroll
    for (int i = 0; i < 4; i++) {
      const int row = wm * 64 + i * 16 + ql;
      af[i] = *(const bfrag*)&As[cur][row * 32 + ((lg ^ ((row >> 1) & 3)) * 8)];
    }
#pragma unroll
    for (int j = 0; j < 4; j++) {
      const int row = wn * 64 + j * 16 + ql;
      bfr[j] = *(const bfrag*)&Bs[cur][row * 32 + ((lg ^ ((row >> 1) & 3)) * 8)];
    }
#pragma unroll
    for (int i = 0; i < 4; i++)
#pragma unroll
      for (int j = 0; j < 4; j++)
        acc[i][j] = mfma16(af[i], bfr[j], acc[i][j]);
    __syncthreads();
    cur ^= 1;
  }

#pragma unroll
  for (int i = 0; i < 4; i++) {
    const int row = m0 + wm * 64 + i * 16 + lg * 4;
#pragma unroll
    for (int j = 0; j < 4; j++) {
      const int col = n0 + wn * 64 + j * 16 + ql;
      const float bv = bias[col];
#pragma unroll
      for (int r = 0; r < 4; r++) {
        float v = acc[i][j][r] + bv;
        const size_t idx = (size_t)(row + r) * N + col;
        if (EPI == 0) {
          outB[idx] = (bf16)v;
        } else if (EPI == 1) {
          outF[idx] = v + resid[idx];
        } else {
          outB[idx] = (bf16)(v / (1.0f + __expf(-1.702f * v)));
        }
      }
    }
  }
}

// ---------------------------------------------------------------- GEMM 64x64 (out, proj) — round-14 proven
// (M-contiguous XCD placement: per-XCD A-slice 4MB = its L2.)
template <int EPI>
__global__ __launch_bounds__(256, 4) void gemm_bt64(
    const bf16* __restrict__ A, const bf16* __restrict__ B,
    const float* __restrict__ bias, const float* __restrict__ resid,
    float* __restrict__ outF, bf16* __restrict__ outB,
    int M, int N, int K) {
  __shared__ bf16 As[2][64 * 64];
  __shared__ bf16 Bs[2][64 * 64];
  const int tid = threadIdx.x;
  const int lane = tid & 63, w = tid >> 6;
  const int wm = w >> 1, wn = w & 1;
  const int ql = lane & 15, lg = lane >> 4;
  const int bid = blockIdx.x;
  const int k8 = bid & 7, j8 = bid >> 3;
  const int m0 = (k8 * 8 + (j8 & 7)) * 64;
  const int n0 = (j8 >> 3) * 64;

  ffrag acc[2][2];
#pragma unroll
  for (int i = 0; i < 2; i++)
#pragma unroll
    for (int j = 0; j < 2; j++) acc[i][j] = ffrag{0.f, 0.f, 0.f, 0.f};

  const int r0 = tid >> 3;
  const int jsw = ((tid & 7) ^ (r0 & 7)) * 8;
  const bf16* a0 = A + (size_t)(m0 + r0) * K + jsw;
  const bf16* a1 = A + (size_t)(m0 + 32 + r0) * K + jsw;
  const bf16* b0 = B + (size_t)(n0 + r0) * K + jsw;
  const bf16* b1 = B + (size_t)(n0 + 32 + r0) * K + jsw;
  const int lo = tid * 8;

  auto STAGE = [&](int bs, int kk) {
    gload_lds16(a0 + kk, &As[bs][lo]);
    gload_lds16(a1 + kk, &As[bs][2048 + lo]);
    gload_lds16(b0 + kk, &Bs[bs][lo]);
    gload_lds16(b1 + kk, &Bs[bs][2048 + lo]);
  };

  STAGE(0, 0);
  __syncthreads();

  int cur = 0;
  for (int k0 = 0; k0 < K; k0 += 64) {
    if (k0 + 64 < K) STAGE(cur ^ 1, k0 + 64);
    bfrag af[2][2], bfr[2][2];
#pragma unroll
    for (int i = 0; i < 2; i++) {
      const int row = wm * 32 + i * 16 + ql;
      const int r7 = row & 7;
#pragma unroll
      for (int kc = 0; kc < 2; kc++)
        af[i][kc] = *(const bfrag*)&As[cur][row * 64 + (((lg + 4 * kc) ^ r7) * 8)];
    }
#pragma unroll
    for (int j = 0; j < 2; j++) {
      const int row = wn * 32 + j * 16 + ql;
      const int r7 = row & 7;
#pragma unroll
      for (int kc = 0; kc < 2; kc++)
        bfr[j][kc] = *(const bfrag*)&Bs[cur][row * 64 + (((lg + 4 * kc) ^ r7) * 8)];
    }
#pragma unroll
    for (int kc = 0; kc < 2; kc++)
#pragma unroll
      for (int i = 0; i < 2; i++)
#pragma unroll
        for (int j = 0; j < 2; j++)
          acc[i][j] = mfma16(af[i][kc], bfr[j][kc], acc[i][j]);
    __syncthreads();
    cur ^= 1;
  }

#pragma unroll
  for (int i = 0; i < 2; i++) {
    const int row = m0 + wm * 32 + i * 16 + lg * 4;
#pragma unroll
    for (int j = 0; j < 2; j++) {
      const int col = n0 + wn * 32 + j * 16 + ql;
      const float bv = bias[col];
#pragma unroll
      for (int r = 0; r < 4; r++) {
        float v = acc[i][j][r] + bv;
        const size_t idx = (size_t)(row + r) * N + col;
        if (EPI == 0) {
          outB[idx] = (bf16)v;
        } else if (EPI == 1) {
          outF[idx] = v + resid[idx];
        } else {
          outB[idx] = (bf16)(v / (1.0f + __expf(-1.702f * v)));
        }
      }
    }
  }
}

// ---------------------------------------------------------------- V transpose: qkv V-part -> VT[b][h][d][s]
__global__ __launch_bounds__(256) void transpose_v(const bf16* __restrict__ qkv,
                                                   bf16* __restrict__ vt) {
  __shared__ bf16 T[64 * 66];
  const int tid = threadIdx.x;
  const int bh = blockIdx.y, b = bh >> 4, h = bh & 15;
  const int s0 = blockIdx.x * 64;
  const bf16* src = qkv + (size_t)b * SEQ * 3072 + 2048 + h * 64;

  const int sl = tid >> 3, c = tid & 7;
#pragma unroll
  for (int p = 0; p < 2; p++) {
    const int s = sl + p * 32;
    const bfrag v = *(const bfrag*)(src + (size_t)(s0 + s) * 3072 + c * 8);
#pragma unroll
    for (int e = 0; e < 8; e++) T[s * 66 + c * 8 + e] = v[e];
  }
  __syncthreads();
  bf16* dst = vt + (size_t)bh * 64 * 1024;
#pragma unroll
  for (int p = 0; p < 2; p++) {
    const int d = sl + p * 32;
    bfrag o;
#pragma unroll
    for (int e = 0; e < 8; e++) o[e] = T[(c * 8 + e) * 66 + d];
    *(bfrag*)(dst + (size_t)d * 1024 + s0 + c * 8) = o;
  }
}

// ---------------------------------------------------------------- flash attention v7 (round-13/14 proven)
// 32x32 swapped-QK, in-register P via cvt_pk + shfl_xor(.,32), defer-max,
// log2-domain softmax, lane-local lrun, single K/V LDS buffer.
__global__ __launch_bounds__(256, 2) void flash_attn(const bf16* __restrict__ qkv,
                                                     const bf16* __restrict__ vt,
                                                     bf16* __restrict__ o) {
  __shared__ bf16 Kl[128 * 64];
  __shared__ bf16 Vl[64 * 128];
  __shared__ float RB[4][32];
  const int tid = threadIdx.x, lane = tid & 63, wid = tid >> 6;
  const int l31 = lane & 31, hi = lane >> 5;
  const int flat = xcd_remap(blockIdx.y * 8 + blockIdx.x, 512);
  const int qblk = flat & 7, bh = flat >> 3, b = bh >> 4, h = bh & 15;
  const int qb0 = qblk * 128 + wid * 32;
  const size_t headq = (size_t)b * SEQ * 3072 + (size_t)h * 64;

  const bf16* qp = qkv + headq + (size_t)(qb0 + l31) * 3072 + hi * 8;
  bfrag qb[4];
#pragma unroll
  for (int t = 0; t < 4; t++) qb[t] = *(const bfrag*)(qp + t * 16);

  float mrun = -1e30f, lrun = 0.0f;
  f32x16 oacc[2];
#pragma unroll
  for (int r = 0; r < 16; r++) { oacc[0][r] = 0.f; oacc[1][r] = 0.f; }

  const int ksrc = ((tid & 7) ^ ((tid >> 3) & 7) ^ wid) * 8;
  const bf16* kp = qkv + headq + 1024 + (size_t)(tid >> 3) * 3072 + ksrc;
  const bf16* vhead = vt + (size_t)bh * 64 * 1024;
  const int xlane = (l31 & 7) ^ (l31 >> 3);

  for (int kt = 0; kt < SEQ; kt += 128) {
#pragma unroll
    for (int pp = 0; pp < 4; pp++)
      gload_lds16(kp + (size_t)(kt + pp * 32) * 3072, &Kl[pp * 2048 + tid * 8]);
#pragma unroll
    for (int pp = 0; pp < 4; pp++) {
      const int vr = pp * 16 + (tid >> 4);
      const int gc = (tid & 15) ^ ((tid >> 4) & 7) ^ ((pp * 2 + (tid >> 7)) & 3);
      gload_lds16(vhead + (size_t)vr * 1024 + kt + gc * 8, &Vl[(pp * 256 + tid) * 8]);
    }
    __syncthreads();

    f32x16 sacc[4];
#pragma unroll
    for (int s = 0; s < 4; s++)
#pragma unroll
      for (int r = 0; r < 16; r++) sacc[s][r] = 0.f;
    __builtin_amdgcn_s_setprio(1);
#pragma unroll
    for (int s = 0; s < 4; s++) {
      const int krow = s * 32 + l31;
#pragma unroll
      for (int t = 0; t < 4; t++) {
        const int ch = (t * 2) ^ hi ^ xlane;
        const bfrag kf = *(const bfrag*)&Kl[krow * 64 + ch * 8];
        sacc[s] = mfma32(kf, qb[t], sacc[s]);
      }
    }
    __builtin_amdgcn_s_setprio(0);

    float lm = sacc[0][0];
#pragma unroll
    for (int s = 0; s < 4; s++)
#pragma unroll
      for (int r = 0; r < 16; r++) lm = fmaxf(lm, sacc[s][r]);

    if (!__all(lm - mrun <= 8.0f)) {
      const float mx = fmaxf(lm, __shfl_xor(lm, 32));
      const float mnew = fmaxf(mrun, mx);
      const float corr = exp2f(mrun - mnew);
      mrun = mnew;
      lrun *= corr;
      if (!hi) RB[wid][l31] = corr;
#pragma unroll
      for (int r = 0; r < 16; r++) {
        const float c = RB[wid][(r & 3) + 8 * (r >> 2) + 4 * hi];
        oacc[0][r] *= c;
        oacc[1][r] *= c;
      }
    }

#pragma unroll
    for (int s = 0; s < 4; s++) {
      float p[16];
#pragma unroll
      for (int r = 0; r < 16; r++) p[r] = exp2f(sacc[s][r] - mrun);
#pragma unroll
      for (int r = 0; r < 16; r++) lrun += p[r];
      const unsigned A = cvt_pk(p[0], p[1]),  B = cvt_pk(p[2], p[3]);
      const unsigned C = cvt_pk(p[4], p[5]),  D = cvt_pk(p[6], p[7]);
      const unsigned E = cvt_pk(p[8], p[9]),  F = cvt_pk(p[10], p[11]);
      const unsigned G = cvt_pk(p[12], p[13]), H = cvt_pk(p[14], p[15]);
      const unsigned x1 = __shfl_xor(hi ? A : C, 32);
      const unsigned x2 = __shfl_xor(hi ? B : D, 32);
      const unsigned x3 = __shfl_xor(hi ? E : G, 32);
      const unsigned x4 = __shfl_xor(hi ? F : H, 32);
      unsigned w0[4] = { hi ? x1 : A, hi ? x2 : B, hi ? C : x1, hi ? D : x2 };
      unsigned w1[4] = { hi ? x3 : E, hi ? x4 : F, hi ? G : x3, hi ? H : x4 };
      const bfrag pa0 = *(const bfrag*)w0;
      const bfrag pa1 = *(const bfrag*)w1;
      __builtin_amdgcn_s_setprio(1);
#pragma unroll
      for (int db = 0; db < 2; db++) {
        const int vrow = db * 32 + l31;
        const bfrag vf0 = *(const bfrag*)&Vl[vrow * 128 + ((((2 * s) * 2) ^ hi ^ xlane) & 15) * 8];
        oacc[db] = mfma32(pa0, vf0, oacc[db]);
        const bfrag vf1 = *(const bfrag*)&Vl[vrow * 128 + ((((2 * s + 1) * 2) ^ hi ^ xlane) & 15) * 8];
        oacc[db] = mfma32(pa1, vf1, oacc[db]);
      }
      __builtin_amdgcn_s_setprio(0);
    }
    __syncthreads();
  }

  const float lsum = lrun + __shfl_xor(lrun, 32);
  if (!hi) RB[wid][l31] = 1.0f / lsum;
#pragma unroll
  for (int r = 0; r < 16; r++) {
    const int qml = (r & 3) + 8 * (r >> 2) + 4 * hi;
    const float rv = RB[wid][qml];
    const size_t orow = (size_t)b * SEQ + qb0 + qml;
    o[orow * 1024 + h * 64 + l31]      = (bf16)(oacc[0][r] * rv);
    o[orow * 1024 + h * 64 + 32 + l31] = (bf16)(oacc[1][r] * rv);
  }
}

// ---------------------------------------------------------------- launch
extern "C" void kernel_launch(void* const* d_in, const int* in_sizes, int n_in,
                              void* d_out, int out_size, void* d_ws, size_t ws_size,
                              hipStream_t stream) {
  (void)in_sizes; (void)n_in; (void)out_size; (void)ws_size;
  const float* x      = (const float*)d_in[0];
  const float* in_w   = (const float*)d_in[1];
  const float* in_b   = (const float*)d_in[2];
  const float* out_w  = (const float*)d_in[3];
  const float* out_b  = (const float*)d_in[4];
  const float* ln1_g  = (const float*)d_in[5];
  const float* ln1_b  = (const float*)d_in[6];
  const float* fc_w   = (const float*)d_in[7];
  const float* fc_b   = (const float*)d_in[8];
  const float* proj_w = (const float*)d_in[9];
  const float* proj_b = (const float*)d_in[10];
  const float* ln2_g  = (const float*)d_in[11];
  const float* ln2_b  = (const float*)d_in[12];
  float* out = (float*)d_out;

  char* p = (char*)d_ws;
  auto alloc = [&](size_t bytes) { char* r = p; p += (bytes + 255) & ~255ull; return r; };
  bf16* w_qkv  = (bf16*)alloc((size_t)3072 * 1024 * 2);
  bf16* w_out  = (bf16*)alloc((size_t)1024 * 1024 * 2);
  bf16* w_fc   = (bf16*)alloc((size_t)4096 * 1024 * 2);
  bf16* w_proj = (bf16*)alloc((size_t)1024 * 4096 * 2);
  float* b_qkv = (float*)alloc((size_t)3072 * 4);
  bf16* hbuf   = (bf16*)alloc((size_t)NTOK * 1024 * 2);   // LN1 out; reused as LN2 out
  float* x2    = (float*)alloc((size_t)NTOK * 1024 * 4);
  bf16* qkv    = (bf16*)alloc((size_t)NTOK * 3072 * 2);
  bf16* aout   = (bf16*)alloc((size_t)NTOK * 1024 * 2);
  bf16* ubuf   = qkv;              // aliases qkv+aout (both dead by GEMM3)
  bf16* vtb    = (bf16*)x2;        // VT [64 bh][64 d][1024 s] = 8MB; x2 written only after flash

  // fold head-scaling AND log2(e) (log2-domain softmax) into q weights+bias
  const float scaling = 0.125f * 1.44269504089f;
  convert_all<<<dim3(1024, 4), 256, 0, stream>>>(
      in_w, w_qkv, 3072 * 1024 / 4,
      out_w, w_out, 1024 * 1024 / 4,
      fc_w, w_fc, 4096 * 1024 / 4,
      proj_w, w_proj, 4096 * 1024 / 4,
      scaling, 1024 * 1024 / 4);
  scale_bias<<<12, 256, 0, stream>>>(in_b, b_qkv, 3072, 1024, scaling);

  ln_row<<<NTOK, 256, 0, stream>>>(x, ln1_g, ln1_b, hbuf);
  gemm_bt<0><<<dim3(32, 24), 256, 0, stream>>>(hbuf, w_qkv, b_qkv, nullptr,
                                               nullptr, qkv, NTOK, 3072, 1024);
  transpose_v<<<dim3(16, 64), 256, 0, stream>>>(qkv, vtb);
  flash_attn<<<dim3(8, 64), 256, 0, stream>>>(qkv, vtb, aout);
  gemm_bt64<1><<<1024, 256, 0, stream>>>(aout, w_out, out_b, x,
                                         x2, nullptr, NTOK, 1024, 1024);
  ln_row<<<NTOK, 256, 0, stream>>>(x2, ln2_g, ln2_b, hbuf);
  gemm_bt<2><<<dim3(32, 32), 256, 0, stream>>>(hbuf, w_fc, fc_b, nullptr,
                                               nullptr, ubuf, NTOK, 4096, 1024);
  gemm_bt64<1><<<1024, 256, 0, stream>>>(ubuf, w_proj, proj_b, x2,
                                         out, nullptr, NTOK, 1024, 4096);
}